// Round 1
// baseline (379.046 us; speedup 1.0000x reference)
//
#include <hip/hip_runtime.h>

#define N_NODES 2048
#define C_CH    128
#define N_SPEC  10

// Coefficient page per (species, channel): dense C3[729][9] + C2[81][9] + C1[9][9]
// = 7371 floats, padded to 7424 (29,696 B, 64B-aligned pages).
#define PAGE        7424
#define CG_OFF_B    (128 * 1024)                               // bytes into d_ws
#define CG_BYTES    ((size_t)N_SPEC * C_CH * PAGE * 4)

// ---------------------------------------------------------------------------
// Kernel 1: bucket nodes by species. Single block; LDS atomics for positions.
// ---------------------------------------------------------------------------
__global__ __launch_bounds__(1024) void bucket_kernel(const int* __restrict__ index,
                                                      int* __restrict__ counts,
                                                      int* __restrict__ lists) {
    __shared__ int sc[N_SPEC];
    const int tid = threadIdx.x;
    if (tid < N_SPEC) sc[tid] = 0;
    __syncthreads();
    for (int n = tid; n < N_NODES; n += blockDim.x) {
        int s = index[n];
        int pos = atomicAdd(&sc[s], 1);
        lists[s * N_NODES + pos] = n;
    }
    __syncthreads();
    if (tid < N_SPEC) counts[tid] = sc[tid];
}

struct Params {
    const float* U3[3]; const float* W3[3];
    const float* U2[3]; const float* W2[3];
    const float* U1[3]; const float* W1[3];
};

// ---------------------------------------------------------------------------
// Kernel 2: precompute coefficient pages into global workspace.
// C[e, sc-page] with e = abj*9+i (C3), 6561+ab*9+i (C2), 7290+a*9+i (C1).
// Same k-ascending summation order as the old buildC -> bit-identical results.
// Grid: 10 species x 16 channel-groups of 8 -> 160 blocks x 256 threads.
// ---------------------------------------------------------------------------
__global__ __launch_bounds__(256) void coef_kernel(Params p, float* __restrict__ Cg) {
    const int s  = blockIdx.x >> 4;
    const int c0 = (blockIdx.x & 15) << 3;
    for (int e = threadIdx.x; e < 7371; e += 256) {
        int rgn, r;
        if (e < 6561)      { rgn = 0; r = e; }
        else if (e < 7290) { rgn = 1; r = e - 6561; }
        else               { rgn = 2; r = e - 7290; }
        const int abn = r / 9;
        const int i   = r - abn * 9;
        const int iri   = (i == 0) ? 0 : (i < 4 ? 1 : 2);
        const int irdim = (i == 0) ? 1 : (i < 4 ? 3 : 5);
        const int il    = (i == 0) ? 0 : (i < 4 ? i - 1 : i - 4);
        int mul;
        const float *u, *w;
        if (rgn == 0) {
            mul = (iri == 0) ? 10 : (iri == 1) ? 11 : 13;
            u = p.U3[iri]; w = p.W3[iri];
        } else if (rgn == 1) {
            mul = (iri == 1) ? 2 : 3;
            u = p.U2[iri]; w = p.W2[iri];
        } else {
            mul = 1;
            u = p.U1[iri]; w = p.W1[iri];
        }
        float acc[8];
#pragma unroll
        for (int cc = 0; cc < 8; ++cc) acc[cc] = 0.f;
        for (int k = 0; k < mul; ++k) {
            const float uv = u[(abn * mul + k) * irdim + il];
            const float* wp = w + (s * mul + k) * C_CH + c0;
#pragma unroll
            for (int cc = 0; cc < 8; ++cc) acc[cc] += uv * wp[cc];
        }
#pragma unroll
        for (int cc = 0; cc < 8; ++cc)
            Cg[(size_t)(s * C_CH + c0 + cc) * PAGE + e] = acc[cc];
    }
}

// dynamic index into a register array without scratch: cndmask chain (a is 0..8)
__device__ inline float selx(const float x[9], int a) {
    float r = x[0];
    r = (a == 1) ? x[1] : r;
    r = (a == 2) ? x[2] : r;
    r = (a == 3) ? x[3] : r;
    r = (a == 4) ? x[4] : r;
    r = (a == 5) ? x[5] : r;
    r = (a == 6) ? x[6] : r;
    r = (a == 7) ? x[7] : r;
    r = (a == 8) ? x[8] : r;
    return r;
}

// ---------------------------------------------------------------------------
// Kernel 3: evaluation. One block per (species, channel), 256 threads, 1 node
// per thread per pass. Coefficients are read with block-uniform addresses from
// the precomputed page -> scalar (SMEM) path, no LDS at all.
// ---------------------------------------------------------------------------
__global__ __launch_bounds__(256) void sc_eval_kernel(const float* __restrict__ nf,
                                                      const int* __restrict__ counts,
                                                      const int* __restrict__ lists,
                                                      const float* __restrict__ Cg,
                                                      float* __restrict__ out) {
    const int s = blockIdx.x % N_SPEC;
    const int c = blockIdx.x / N_SPEC;
    const float* __restrict__ Cp = Cg + (size_t)(s * C_CH + c) * PAGE;
    const int cnt = counts[s];

    for (int base = 0; base < cnt; base += 256) {
        const int i0 = base + threadIdx.x;
        const int m0 = (i0 < cnt) ? lists[s * N_NODES + i0] : -1;
        const float* xp = nf + ((long)(m0 < 0 ? 0 : m0) * C_CH + c) * 9;
        float x[9];
#pragma unroll
        for (int j = 0; j < 9; ++j) x[j] = xp[j];

        float o[9];
#pragma unroll
        for (int i = 0; i < 9; ++i) o[i] = 0.f;

#pragma unroll 1  // keep a-loop rolled: per-a body (~1000 instrs) stays I$-resident
        for (int a = 0; a < 9; ++a) {
            const float xa = selx(x, a);
            float q[9];
#pragma unroll
            for (int i = 0; i < 9; ++i) q[i] = Cp[7290 + a * 9 + i];
#pragma unroll
            for (int b = 0; b < 9; ++b) {
                float t[9];
#pragma unroll
                for (int i = 0; i < 9; ++i) t[i] = Cp[6561 + (a * 9 + b) * 9 + i];
#pragma unroll
                for (int j = 0; j < 9; ++j) {
                    const float xj = x[j];
                    const int b3 = ((a * 9 + b) * 9 + j) * 9;
#pragma unroll
                    for (int i = 0; i < 9; ++i) t[i] += Cp[b3 + i] * xj;
                }
                const float xb = x[b];
#pragma unroll
                for (int i = 0; i < 9; ++i) q[i] += t[i] * xb;
            }
#pragma unroll
            for (int i = 0; i < 9; ++i) o[i] += q[i] * xa;
        }

        if (m0 >= 0) {
            float* op = out + ((long)m0 * C_CH + c) * 9;
#pragma unroll
            for (int i = 0; i < 9; ++i) op[i] = o[i];
        }
    }
}

// ---------------------------------------------------------------------------
// Fallback path (old verified kernel) in case ws_size can't hold the pages.
// ---------------------------------------------------------------------------
template <int NAB, int MUL, int IRD, int IOFF>
__device__ inline void buildC(const float* __restrict__ u, const float* __restrict__ w,
                              int s, int c, float* __restrict__ sMain, float* __restrict__ sB) {
    const int tid = threadIdx.x;
    const float* wp = w + (s * MUL) * C_CH + c;
    for (int e = tid; e < NAB * IRD; e += 128) {
        int abj = e / IRD;
        int il  = e - abj * IRD;
        const float* up = u + (abj * MUL) * IRD + il;
        float acc = 0.f;
#pragma unroll
        for (int k = 0; k < MUL; ++k)
            acc += up[k * IRD] * wp[k * C_CH];
        int i = IOFF + il;
        if (i < 8) sMain[abj * 8 + i] = acc;
        else       sB[abj] = acc;
    }
}

__global__ __launch_bounds__(128) void sc_kernel(const float* __restrict__ nf,
                                                 const int* __restrict__ counts,
                                                 const int* __restrict__ lists,
                                                 Params p,
                                                 float* __restrict__ out) {
    __shared__ __align__(16) float sC3[729 * 8];
    __shared__ float sC3b[729];
    __shared__ __align__(16) float sC2[81 * 8];
    __shared__ float sC2b[81];
    __shared__ __align__(16) float sC1[9 * 8];
    __shared__ float sC1b[9];

    const int s = blockIdx.x % N_SPEC;
    const int c = blockIdx.x / N_SPEC;
    const int tid = threadIdx.x;

    buildC<729, 10, 1, 0>(p.U3[0], p.W3[0], s, c, sC3, sC3b);
    buildC<729, 11, 3, 1>(p.U3[1], p.W3[1], s, c, sC3, sC3b);
    buildC<729, 13, 5, 4>(p.U3[2], p.W3[2], s, c, sC3, sC3b);
    buildC<81, 3, 1, 0>(p.U2[0], p.W2[0], s, c, sC2, sC2b);
    buildC<81, 2, 3, 1>(p.U2[1], p.W2[1], s, c, sC2, sC2b);
    buildC<81, 3, 5, 4>(p.U2[2], p.W2[2], s, c, sC2, sC2b);
    buildC<9, 1, 1, 0>(p.U1[0], p.W1[0], s, c, sC1, sC1b);
    buildC<9, 1, 3, 1>(p.U1[1], p.W1[1], s, c, sC1, sC1b);
    buildC<9, 1, 5, 4>(p.U1[2], p.W1[2], s, c, sC1, sC1b);
    __syncthreads();

    const int cnt = counts[s];
    const float4* C3v = (const float4*)sC3;
    const float4* C2v = (const float4*)sC2;
    const float4* C1v = (const float4*)sC1;

    for (int base = 0; base < cnt; base += 256) {
        const int i0 = base + tid;
        const int i1 = base + 128 + tid;
        const int m0 = (i0 < cnt) ? lists[s * N_NODES + i0] : -1;
        const int m1 = (i1 < cnt) ? lists[s * N_NODES + i1] : -1;

        const float* x0p = nf + ((long)(m0 < 0 ? 0 : m0) * C_CH + c) * 9;
        const float* x1p = nf + ((long)(m1 < 0 ? 0 : m1) * C_CH + c) * 9;
        float x0[9], x1[9];
#pragma unroll
        for (int j = 0; j < 9; ++j) { x0[j] = x0p[j]; x1[j] = x1p[j]; }

        float4 o0a = {0, 0, 0, 0}, o0b = {0, 0, 0, 0};
        float4 o1a = {0, 0, 0, 0}, o1b = {0, 0, 0, 0};
        float o08 = 0.f, o18 = 0.f;

#pragma unroll 1
        for (int a = 0; a < 9; ++a) {
            const float xa0 = selx(x0, a);
            const float xa1 = selx(x1, a);
            const float4 c1a = C1v[a * 2], c1b = C1v[a * 2 + 1];
            const float  c18 = sC1b[a];
            float4 q0a = c1a, q0b = c1b; float q08 = c18;
            float4 q1a = c1a, q1b = c1b; float q18 = c18;
#pragma unroll
            for (int b = 0; b < 9; ++b) {
                const int ab = a * 9 + b;
                const float4 c2a = C2v[ab * 2], c2b = C2v[ab * 2 + 1];
                const float  c28 = sC2b[ab];
                float4 t0a = c2a, t0b = c2b; float t08 = c28;
                float4 t1a = c2a, t1b = c2b; float t18 = c28;
#pragma unroll
                for (int j = 0; j < 9; ++j) {
                    const int abj = ab * 9 + j;
                    const float4 ca = C3v[abj * 2];
                    const float4 cb = C3v[abj * 2 + 1];
                    const float  c8 = sC3b[abj];
                    t0a += ca * x0[j]; t0b += cb * x0[j]; t08 += c8 * x0[j];
                    t1a += ca * x1[j]; t1b += cb * x1[j]; t18 += c8 * x1[j];
                }
                q0a += t0a * x0[b]; q0b += t0b * x0[b]; q08 += t08 * x0[b];
                q1a += t1a * x1[b]; q1b += t1b * x1[b]; q18 += t18 * x1[b];
            }
            o0a += q0a * xa0; o0b += q0b * xa0; o08 += q08 * xa0;
            o1a += q1a * xa1; o1b += q1b * xa1; o18 += q18 * xa1;
        }

        if (m0 >= 0) {
            float* op = out + ((long)m0 * C_CH + c) * 9;
            op[0] = o0a.x; op[1] = o0a.y; op[2] = o0a.z; op[3] = o0a.w;
            op[4] = o0b.x; op[5] = o0b.y; op[6] = o0b.z; op[7] = o0b.w;
            op[8] = o08;
        }
        if (m1 >= 0) {
            float* op = out + ((long)m1 * C_CH + c) * 9;
            op[0] = o1a.x; op[1] = o1a.y; op[2] = o1a.z; op[3] = o1a.w;
            op[4] = o1b.x; op[5] = o1b.y; op[6] = o1b.z; op[7] = o1b.w;
            op[8] = o18;
        }
    }
}

// ---------------------------------------------------------------------------
extern "C" void kernel_launch(void* const* d_in, const int* in_sizes, int n_in,
                              void* d_out, int out_size, void* d_ws, size_t ws_size,
                              hipStream_t stream) {
    const float* nf   = (const float*)d_in[0];
    const int* index  = (const int*)d_in[1];

    Params p;
    p.U3[0] = (const float*)d_in[2];  p.W3[0] = (const float*)d_in[3];
    p.U3[1] = (const float*)d_in[4];  p.W3[1] = (const float*)d_in[5];
    p.U3[2] = (const float*)d_in[6];  p.W3[2] = (const float*)d_in[7];
    p.U2[0] = (const float*)d_in[8];  p.W2[0] = (const float*)d_in[9];
    p.U2[1] = (const float*)d_in[10]; p.W2[1] = (const float*)d_in[11];
    p.U2[2] = (const float*)d_in[12]; p.W2[2] = (const float*)d_in[13];
    p.U1[0] = (const float*)d_in[14]; p.W1[0] = (const float*)d_in[15];
    p.U1[1] = (const float*)d_in[16]; p.W1[1] = (const float*)d_in[17];
    p.U1[2] = (const float*)d_in[18]; p.W1[2] = (const float*)d_in[19];

    int* counts = (int*)d_ws;        // 16 ints (aligned region start)
    int* lists  = (int*)d_ws + 16;   // 10 * 2048 ints, ends at 81,984 B

    bucket_kernel<<<1, 1024, 0, stream>>>(index, counts, lists);

    if (ws_size >= (size_t)CG_OFF_B + CG_BYTES) {
        float* Cg = (float*)((char*)d_ws + CG_OFF_B);
        coef_kernel<<<N_SPEC * 16, 256, 0, stream>>>(p, Cg);
        sc_eval_kernel<<<N_SPEC * C_CH, 256, 0, stream>>>(nf, counts, lists, Cg,
                                                          (float*)d_out);
    } else {
        sc_kernel<<<N_SPEC * C_CH, 128, 0, stream>>>(nf, counts, lists, p,
                                                     (float*)d_out);
    }
}

// Round 2
// 345.059 us; speedup vs baseline: 1.0985x; 1.0985x over previous
//
#include <hip/hip_runtime.h>

#define N_NODES 2048
#define C_CH    128
#define N_SPEC  10

// --- symmetric-reduced coefficient page per (species, channel) ---------------
// S3[165][9] (sorted a<=b<=j, lex order) | S2[45][9] (sorted a<=b) | S1[9][9]
// = 1971 floats, padded to 2048 (8 KB pages).
#define PAGE2   2048
#define S2OFF   1485
#define S1OFF   1890

// --- symmetrized-U region layout (floats, within d_ws at US_OFF_B) ----------
// Us3_ir[n3][k][il], Us2_ir[n2][k][il]
#define US3_0   0        // 165*10*1 = 1650
#define US3_1   1650     // 165*11*3 = 5445
#define US3_2   7095     // 165*13*5 = 10725
#define US2_0   17820    // 45*3*1   = 135
#define US2_1   17955    // 45*2*3   = 270
#define US2_2   18225    // 45*3*5   = 675
#define US_TOT  18900

#define US_OFF_B  (128 * 1024)
#define CG_OFF_B  (256 * 1024)
#define CG_BYTES  ((size_t)N_SPEC * C_CH * PAGE2 * 4)

// ---------------------------------------------------------------------------
// Kernel 1: bucket nodes by species. Single block; LDS atomics for positions.
// ---------------------------------------------------------------------------
__global__ __launch_bounds__(1024) void bucket_kernel(const int* __restrict__ index,
                                                      int* __restrict__ counts,
                                                      int* __restrict__ lists) {
    __shared__ int sc[N_SPEC];
    const int tid = threadIdx.x;
    if (tid < N_SPEC) sc[tid] = 0;
    __syncthreads();
    for (int n = tid; n < N_NODES; n += blockDim.x) {
        int s = index[n];
        int pos = atomicAdd(&sc[s], 1);
        lists[s * N_NODES + pos] = n;
    }
    __syncthreads();
    if (tid < N_SPEC) counts[tid] = sc[tid];
}

struct Params {
    const float* U3[3]; const float* W3[3];
    const float* U2[3]; const float* W2[3];
    const float* U1[3]; const float* W1[3];
};

// ---------------------------------------------------------------------------
// Kernel 2: symmetrize U over permutation groups of the feature indices.
// Us3[sorted(a<=b<=j)][k][il] = sum over DISTINCT perms of U3[a'][b'][j'][k][il]
// Us2[sorted(a<=b)][k][il]    = sum over distinct perms of U2.
// One thread per output element (18,900 total).
// ---------------------------------------------------------------------------
__global__ __launch_bounds__(256) void usym_kernel(Params p, float* __restrict__ Us) {
    const int t = blockIdx.x * 256 + threadIdx.x;
    if (t >= US_TOT) return;

    bool is3; int mul, ird, r; const float* u;
    if (t < US3_1)       { is3 = true;  mul = 10; ird = 1; r = t;          u = p.U3[0]; }
    else if (t < US3_2)  { is3 = true;  mul = 11; ird = 3; r = t - US3_1;  u = p.U3[1]; }
    else if (t < US2_0)  { is3 = true;  mul = 13; ird = 5; r = t - US3_2;  u = p.U3[2]; }
    else if (t < US2_1)  { is3 = false; mul = 3;  ird = 1; r = t - US2_0;  u = p.U2[0]; }
    else if (t < US2_2)  { is3 = false; mul = 2;  ird = 3; r = t - US2_1;  u = p.U2[1]; }
    else                 { is3 = false; mul = 3;  ird = 5; r = t - US2_2;  u = p.U2[2]; }

    const int mi  = mul * ird;
    const int n   = r / mi;
    const int rem = r - n * mi;           // k*ird + il

    float acc = 0.f;
    if (is3) {
        int aa = 0, bb = 0, jj = 0, ctr = 0;
        for (int a2 = 0; a2 < 9; ++a2)
            for (int b2 = a2; b2 < 9; ++b2)
                for (int j2 = b2; j2 < 9; ++j2) {
                    if (ctr == n) { aa = a2; bb = b2; jj = j2; }
                    ++ctr;
                }
        int L[6];
        L[0] = (aa * 9 + bb) * 9 + jj; L[1] = (aa * 9 + jj) * 9 + bb;
        L[2] = (bb * 9 + aa) * 9 + jj; L[3] = (bb * 9 + jj) * 9 + aa;
        L[4] = (jj * 9 + aa) * 9 + bb; L[5] = (jj * 9 + bb) * 9 + aa;
        for (int m = 0; m < 6; ++m) {
            bool dup = false;
            for (int mm = 0; mm < m; ++mm) dup = dup || (L[mm] == L[m]);
            if (!dup) acc += u[L[m] * mi + rem];
        }
    } else {
        int aa = 0, bb = 0, ctr = 0;
        for (int a2 = 0; a2 < 9; ++a2)
            for (int b2 = a2; b2 < 9; ++b2) {
                if (ctr == n) { aa = a2; bb = b2; }
                ++ctr;
            }
        acc = u[(aa * 9 + bb) * mi + rem];
        if (aa != bb) acc += u[(bb * 9 + aa) * mi + rem];
    }
    Us[t] = acc;
}

// ---------------------------------------------------------------------------
// Kernel 3: build symmetric coefficient pages.
// C[e, (s,c)-page] = sum_k Us[row, k, il] * W[s, k, c].
// Grid: 10 species x 64 channel-pairs = 640 blocks x 256 threads.
// ---------------------------------------------------------------------------
__global__ __launch_bounds__(256) void coef_kernel(Params p, const float* __restrict__ Us,
                                                   float* __restrict__ Cg) {
    const int s  = blockIdx.x / 64;
    const int c0 = (blockIdx.x % 64) * 2;

    for (int e = threadIdx.x; e < 1971; e += 256) {
        int rgn, row, i;
        if (e < S2OFF)      { rgn = 0; row = e / 9;           i = e % 9; }
        else if (e < S1OFF) { rgn = 1; row = (e - S2OFF) / 9; i = (e - S2OFF) % 9; }
        else                { rgn = 2; row = (e - S1OFF) / 9; i = (e - S1OFF) % 9; }

        const int iri = (i == 0) ? 0 : (i < 4 ? 1 : 2);
        const int ird = (i == 0) ? 1 : (i < 4 ? 3 : 5);
        const int il  = (i == 0) ? 0 : (i < 4 ? (i - 1) : (i - 4));

        int mul; const float* ub; const float* w;
        if (rgn == 0) {
            mul = (iri == 0) ? 10 : ((iri == 1) ? 11 : 13);
            ub  = Us + ((iri == 0) ? US3_0 : (iri == 1) ? US3_1 : US3_2)
                     + (row * mul) * ird + il;
            w   = p.W3[iri];
        } else if (rgn == 1) {
            mul = (iri == 1) ? 2 : 3;
            ub  = Us + ((iri == 0) ? US2_0 : (iri == 1) ? US2_1 : US2_2)
                     + (row * mul) * ird + il;
            w   = p.W2[iri];
        } else {
            mul = 1;
            ub  = p.U1[iri] + row * ird + il;
            w   = p.W1[iri];
        }

        float a0 = 0.f, a1 = 0.f;
        const float* wp = w + (s * mul) * C_CH + c0;
        for (int k = 0; k < mul; ++k) {
            const float uv = ub[k * ird];
            a0 += uv * wp[k * C_CH];
            a1 += uv * wp[k * C_CH + 1];
        }
        Cg[(size_t)(s * C_CH + c0) * PAGE2 + e]     = a0;
        Cg[(size_t)(s * C_CH + c0 + 1) * PAGE2 + e] = a1;
    }
}

// ---------------------------------------------------------------------------
// Kernel 4: evaluation over sorted monomials, fully unrolled.
// All coefficient offsets are compile-time constants from a block-uniform page
// base -> s_load streams + v_fmac(sgpr, vgpr); x[] indices all static.
// out[i] = sum_{a<=b<=j} S3*x_a x_b x_j + sum_{a<=b} S2*x_a x_b + sum_a S1*x_a
// ---------------------------------------------------------------------------
__global__ __launch_bounds__(256) void sc_eval_kernel(const float* __restrict__ nf,
                                                      const int* __restrict__ counts,
                                                      const int* __restrict__ lists,
                                                      const float* __restrict__ Cg,
                                                      float* __restrict__ out) {
    const int s = blockIdx.x / C_CH;   // 128 consecutive blocks share a species
    const int c = blockIdx.x % C_CH;   // -> same node rows, L2 locality
    const float* __restrict__ Cp = Cg + (size_t)(s * C_CH + c) * PAGE2;
    const int cnt = counts[s];

    for (int base = 0; base < cnt; base += 256) {
        const int i0 = base + threadIdx.x;
        const int m0 = (i0 < cnt) ? lists[s * N_NODES + i0] : -1;
        const float* xp = nf + ((long)(m0 < 0 ? 0 : m0) * C_CH + c) * 9;
        float x[9];
#pragma unroll
        for (int j = 0; j < 9; ++j) x[j] = xp[j];

        float o[9];
#pragma unroll
        for (int i = 0; i < 9; ++i) o[i] = 0.f;

        int n3 = 0, n2 = 0;
#pragma unroll
        for (int a = 0; a < 9; ++a) {
            const float xa = x[a];
#pragma unroll
            for (int i = 0; i < 9; ++i) o[i] += Cp[S1OFF + a * 9 + i] * xa;
#pragma unroll
            for (int b = a; b < 9; ++b) {
                const float xab = xa * x[b];
#pragma unroll
                for (int i = 0; i < 9; ++i) o[i] += Cp[S2OFF + n2 * 9 + i] * xab;
#pragma unroll
                for (int j = b; j < 9; ++j) {
                    const float m = xab * x[j];
#pragma unroll
                    for (int i = 0; i < 9; ++i) o[i] += Cp[n3 * 9 + i] * m;
                    ++n3;
                }
                ++n2;
            }
        }

        if (m0 >= 0) {
            float* op = out + ((long)m0 * C_CH + c) * 9;
#pragma unroll
            for (int i = 0; i < 9; ++i) op[i] = o[i];
        }
    }
}

// ---------------------------------------------------------------------------
// Fallback path (round-0 verified kernel) in case ws_size is too small.
// ---------------------------------------------------------------------------
template <int NAB, int MUL, int IRD, int IOFF>
__device__ inline void buildC(const float* __restrict__ u, const float* __restrict__ w,
                              int s, int c, float* __restrict__ sMain, float* __restrict__ sB) {
    const int tid = threadIdx.x;
    const float* wp = w + (s * MUL) * C_CH + c;
    for (int e = tid; e < NAB * IRD; e += 128) {
        int abj = e / IRD;
        int il  = e - abj * IRD;
        const float* up = u + (abj * MUL) * IRD + il;
        float acc = 0.f;
#pragma unroll
        for (int k = 0; k < MUL; ++k)
            acc += up[k * IRD] * wp[k * C_CH];
        int i = IOFF + il;
        if (i < 8) sMain[abj * 8 + i] = acc;
        else       sB[abj] = acc;
    }
}

__device__ inline float selx(const float x[9], int a) {
    float r = x[0];
    r = (a == 1) ? x[1] : r; r = (a == 2) ? x[2] : r; r = (a == 3) ? x[3] : r;
    r = (a == 4) ? x[4] : r; r = (a == 5) ? x[5] : r; r = (a == 6) ? x[6] : r;
    r = (a == 7) ? x[7] : r; r = (a == 8) ? x[8] : r;
    return r;
}

__global__ __launch_bounds__(128) void sc_kernel(const float* __restrict__ nf,
                                                 const int* __restrict__ counts,
                                                 const int* __restrict__ lists,
                                                 Params p,
                                                 float* __restrict__ out) {
    __shared__ __align__(16) float sC3[729 * 8];
    __shared__ float sC3b[729];
    __shared__ __align__(16) float sC2[81 * 8];
    __shared__ float sC2b[81];
    __shared__ __align__(16) float sC1[9 * 8];
    __shared__ float sC1b[9];

    const int s = blockIdx.x % N_SPEC;
    const int c = blockIdx.x / N_SPEC;
    const int tid = threadIdx.x;

    buildC<729, 10, 1, 0>(p.U3[0], p.W3[0], s, c, sC3, sC3b);
    buildC<729, 11, 3, 1>(p.U3[1], p.W3[1], s, c, sC3, sC3b);
    buildC<729, 13, 5, 4>(p.U3[2], p.W3[2], s, c, sC3, sC3b);
    buildC<81, 3, 1, 0>(p.U2[0], p.W2[0], s, c, sC2, sC2b);
    buildC<81, 2, 3, 1>(p.U2[1], p.W2[1], s, c, sC2, sC2b);
    buildC<81, 3, 5, 4>(p.U2[2], p.W2[2], s, c, sC2, sC2b);
    buildC<9, 1, 1, 0>(p.U1[0], p.W1[0], s, c, sC1, sC1b);
    buildC<9, 1, 3, 1>(p.U1[1], p.W1[1], s, c, sC1, sC1b);
    buildC<9, 1, 5, 4>(p.U1[2], p.W1[2], s, c, sC1, sC1b);
    __syncthreads();

    const int cnt = counts[s];
    const float4* C3v = (const float4*)sC3;
    const float4* C2v = (const float4*)sC2;
    const float4* C1v = (const float4*)sC1;

    for (int base = 0; base < cnt; base += 256) {
        const int i0 = base + tid;
        const int i1 = base + 128 + tid;
        const int m0 = (i0 < cnt) ? lists[s * N_NODES + i0] : -1;
        const int m1 = (i1 < cnt) ? lists[s * N_NODES + i1] : -1;

        const float* x0p = nf + ((long)(m0 < 0 ? 0 : m0) * C_CH + c) * 9;
        const float* x1p = nf + ((long)(m1 < 0 ? 0 : m1) * C_CH + c) * 9;
        float x0[9], x1[9];
#pragma unroll
        for (int j = 0; j < 9; ++j) { x0[j] = x0p[j]; x1[j] = x1p[j]; }

        float4 o0a = {0, 0, 0, 0}, o0b = {0, 0, 0, 0};
        float4 o1a = {0, 0, 0, 0}, o1b = {0, 0, 0, 0};
        float o08 = 0.f, o18 = 0.f;

#pragma unroll 1
        for (int a = 0; a < 9; ++a) {
            const float xa0 = selx(x0, a);
            const float xa1 = selx(x1, a);
            const float4 c1a = C1v[a * 2], c1b = C1v[a * 2 + 1];
            const float  c18 = sC1b[a];
            float4 q0a = c1a, q0b = c1b; float q08 = c18;
            float4 q1a = c1a, q1b = c1b; float q18 = c18;
#pragma unroll
            for (int b = 0; b < 9; ++b) {
                const int ab = a * 9 + b;
                const float4 c2a = C2v[ab * 2], c2b = C2v[ab * 2 + 1];
                const float  c28 = sC2b[ab];
                float4 t0a = c2a, t0b = c2b; float t08 = c28;
                float4 t1a = c2a, t1b = c2b; float t18 = c28;
#pragma unroll
                for (int j = 0; j < 9; ++j) {
                    const int abj = ab * 9 + j;
                    const float4 ca = C3v[abj * 2];
                    const float4 cb = C3v[abj * 2 + 1];
                    const float  c8 = sC3b[abj];
                    t0a += ca * x0[j]; t0b += cb * x0[j]; t08 += c8 * x0[j];
                    t1a += ca * x1[j]; t1b += cb * x1[j]; t18 += c8 * x1[j];
                }
                q0a += t0a * x0[b]; q0b += t0b * x0[b]; q08 += t08 * x0[b];
                q1a += t1a * x1[b]; q1b += t1b * x1[b]; q18 += t18 * x1[b];
            }
            o0a += q0a * xa0; o0b += q0b * xa0; o08 += q08 * xa0;
            o1a += q1a * xa1; o1b += q1b * xa1; o18 += q18 * xa1;
        }

        if (m0 >= 0) {
            float* op = out + ((long)m0 * C_CH + c) * 9;
            op[0] = o0a.x; op[1] = o0a.y; op[2] = o0a.z; op[3] = o0a.w;
            op[4] = o0b.x; op[5] = o0b.y; op[6] = o0b.z; op[7] = o0b.w;
            op[8] = o08;
        }
        if (m1 >= 0) {
            float* op = out + ((long)m1 * C_CH + c) * 9;
            op[0] = o1a.x; op[1] = o1a.y; op[2] = o1a.z; op[3] = o1a.w;
            op[4] = o1b.x; op[5] = o1b.y; op[6] = o1b.z; op[7] = o1b.w;
            op[8] = o18;
        }
    }
}

// ---------------------------------------------------------------------------
extern "C" void kernel_launch(void* const* d_in, const int* in_sizes, int n_in,
                              void* d_out, int out_size, void* d_ws, size_t ws_size,
                              hipStream_t stream) {
    const float* nf   = (const float*)d_in[0];
    const int* index  = (const int*)d_in[1];

    Params p;
    p.U3[0] = (const float*)d_in[2];  p.W3[0] = (const float*)d_in[3];
    p.U3[1] = (const float*)d_in[4];  p.W3[1] = (const float*)d_in[5];
    p.U3[2] = (const float*)d_in[6];  p.W3[2] = (const float*)d_in[7];
    p.U2[0] = (const float*)d_in[8];  p.W2[0] = (const float*)d_in[9];
    p.U2[1] = (const float*)d_in[10]; p.W2[1] = (const float*)d_in[11];
    p.U2[2] = (const float*)d_in[12]; p.W2[2] = (const float*)d_in[13];
    p.U1[0] = (const float*)d_in[14]; p.W1[0] = (const float*)d_in[15];
    p.U1[1] = (const float*)d_in[16]; p.W1[1] = (const float*)d_in[17];
    p.U1[2] = (const float*)d_in[18]; p.W1[2] = (const float*)d_in[19];

    int* counts = (int*)d_ws;        // 16 ints
    int* lists  = (int*)d_ws + 16;   // 10 * 2048 ints, ends at 81,984 B

    bucket_kernel<<<1, 1024, 0, stream>>>(index, counts, lists);

    if (ws_size >= (size_t)CG_OFF_B + CG_BYTES) {
        float* Us = (float*)((char*)d_ws + US_OFF_B);
        float* Cg = (float*)((char*)d_ws + CG_OFF_B);
        usym_kernel<<<(US_TOT + 255) / 256, 256, 0, stream>>>(p, Us);
        coef_kernel<<<N_SPEC * 64, 256, 0, stream>>>(p, Us, Cg);
        sc_eval_kernel<<<N_SPEC * C_CH, 256, 0, stream>>>(nf, counts, lists, Cg,
                                                          (float*)d_out);
    } else {
        sc_kernel<<<N_SPEC * C_CH, 128, 0, stream>>>(nf, counts, lists, p,
                                                     (float*)d_out);
    }
}